// Round 7
// baseline (312.929 us; speedup 1.0000x reference)
//
#include <hip/hip_runtime.h>
#include <hip/hip_bf16.h>

#define DFEAT 4096
#define NT 64        // K-tiles of 64
#define NITER 32     // 2 K-tiles per iteration

typedef __attribute__((ext_vector_type(8))) short bf16x8;
typedef __attribute__((ext_vector_type(16))) float f32x16;
typedef __attribute__((ext_vector_type(4))) float float4v;

__device__ inline unsigned short f32_to_bf16_rne(float f) {
  union { float f; unsigned u; } v; v.f = f;
  unsigned u = v.u;
  unsigned r = u + 0x7fffu + ((u >> 16) & 1u);
  return (unsigned short)(r >> 16);
}

// Wt[n][k] = psi[k] * sum_r omega[r][n] * g[r][(n-k)&4095], bf16, row-major [4096][4096]
__global__ void build_wt_kernel(const float* __restrict__ psi,
                                const float* __restrict__ omega,
                                const float* __restrict__ g,
                                unsigned short* __restrict__ Wt) {
  int n = blockIdx.x;
  float o0 = omega[n];
  float o1 = omega[DFEAT + n];
  float o2 = omega[2 * DFEAT + n];
  const float* g0 = g;
  const float* g1 = g + DFEAT;
  const float* g2 = g + 2 * DFEAT;
  for (int k = threadIdx.x; k < DFEAT; k += blockDim.x) {
    int idx = (n - k) & (DFEAT - 1);
    float w = o0 * g0[idx] + o1 * g1[idx] + o2 * g2[idx];
    w *= psi[k];
    Wt[(size_t)n * DFEAT + k] = f32_to_bf16_rne(w);
  }
}

// x (f32) -> bf16 bits, 8 elements/thread
__global__ void convert_x_kernel(const float* __restrict__ x,
                                 unsigned short* __restrict__ Xb, int n8) {
  int stride = gridDim.x * blockDim.x;
  for (int i = blockIdx.x * blockDim.x + threadIdx.x; i < n8; i += stride) {
    size_t base = (size_t)i * 8;
    float4v a = *(const float4v*)(x + base);
    float4v b = *(const float4v*)(x + base + 4);
    union { unsigned short s[8]; uint4 v; } o;
#pragma unroll
    for (int j = 0; j < 4; ++j) o.s[j] = f32_to_bf16_rne(a[j]);
#pragma unroll
    for (int j = 0; j < 4; ++j) o.s[4 + j] = f32_to_bf16_rne(b[j]);
    *(uint4*)(Xb + base) = o.v;
  }
}

// Stage one 128x64 bf16 half-tile into LDS (linear dest, inverse-swizzled global
// source chunk: c_src = chunk' ^ (row&7)). 2 x global_load_lds(16B) per thread.
__device__ __forceinline__ void stageHalf(const unsigned short* __restrict__ G,
                                          int rowBase,            // brow/bcol + h*128
                                          unsigned short* halfBase,
                                          int tile, int srow, int sc, int wave) {
#pragma unroll
  for (int i = 0; i < 2; ++i) {
    const unsigned short* src =
        G + ((size_t)(rowBase + i * 64 + srow) << 12) + (tile << 6) + (sc << 3);
    unsigned short* dst = halfBase + i * 4096 + wave * 512;   // lane-uniform base
    __builtin_amdgcn_global_load_lds((const __attribute__((address_space(1))) unsigned int*)src,
                                     (__attribute__((address_space(3))) unsigned int*)dst, 16, 0, 0);
  }
}

// C[M][4096] = A[M][4096] * B[4096][4096]^T + bias; bf16 in, f32 out.
// 8-phase schedule, 256x256 tile, BK=64, 8 waves (2Mx4N), 2 K-tiles/iter,
// 32x32x16 MFMA fragments (4 row-blocks x 2 col-blocks per wave).
__global__ __launch_bounds__(512, 2) void gemm_kernel(
    const unsigned short* __restrict__ A,   // [M][4096] bf16 bits
    const unsigned short* __restrict__ Bm,  // [4096][4096] bf16 bits (Wt)
    const float* __restrict__ bias,
    float* __restrict__ C,
    int M) {
  // [buf][op A=0/B=1][half][128*64 elements] = 128 KiB
  __shared__ unsigned short L[2][2][2][8192];

  const int t = threadIdx.x;
  const int lane = t & 63;
  const int wave = t >> 6;
  const int wm = wave >> 2;    // 0..1  (A-half = wm)
  const int wn = wave & 3;     // 0..3  (B-half = wn>>1)

  int id = blockIdx.x;
  int per = gridDim.x >> 3;               // bijective: grid % 8 == 0
  int swz = (id & 7) * per + (id >> 3);
  int bm = swz >> 4;                      // bm-stripe per XCD (L2/L3 locality, R4-proven)
  int bn = swz & 15;
  const int brow = bm << 8;
  const int bcol = bn << 8;

  // 32x32x16 fragment addressing in a [128][64] half:
  //   A/B: row/col = blk*32 + (lane&31), k = ks*16 + (lane>>5)*8 + e
  //   element offset = row*64 + (((ks*2 + (lane>>5)) ^ (row&7)) << 3)
  const int laneRow = lane & 31;
  const int ch2 = lane >> 5;
  const int x7 = lane & 7;                  // == row&7 for all frag rows
  int ko[4];
#pragma unroll
  for (int ks = 0; ks < 4; ++ks) ko[ks] = (((ks * 2 + ch2) ^ x7) << 3);
  const int bRow = (wn & 1) * 64;
  // staging per-thread constants
  const int srow = t >> 3;                  // 0..63 per call-half
  const int sc = (t & 7) ^ (srow & 7);      // inverse-swizzled source chunk

  const unsigned short* A0h = &L[0][0][wm][0];
  const unsigned short* B0h = &L[0][1][wn >> 1][0];
  const unsigned short* A1h = &L[1][0][wm][0];
  const unsigned short* B1h = &L[1][1][wn >> 1][0];

  f32x16 acc[4][2] = {};
  bf16x8 a[4], b[2][4];

#define RD_A(Hp, rb) do {                                                     \
    _Pragma("unroll")                                                         \
    for (int ks = 0; ks < 4; ++ks)                                            \
      a[ks] = *(const bf16x8*)((Hp) + ((rb) * 32 + laneRow) * 64 + ko[ks]);   \
  } while (0)

#define RD_B(Hp) do {                                                         \
    _Pragma("unroll")                                                         \
    for (int cb = 0; cb < 2; ++cb)                                            \
      _Pragma("unroll")                                                       \
      for (int ks = 0; ks < 4; ++ks)                                          \
        b[cb][ks] = *(const bf16x8*)((Hp) + (bRow + cb * 32 + laneRow) * 64 + ko[ks]); \
  } while (0)

#define MM(rb) do {                                                           \
    __builtin_amdgcn_s_setprio(1);                                            \
    _Pragma("unroll")                                                         \
    for (int ks = 0; ks < 4; ++ks)                                            \
      _Pragma("unroll")                                                       \
      for (int cb = 0; cb < 2; ++cb)                                          \
        acc[rb][cb] = __builtin_amdgcn_mfma_f32_32x32x16_bf16(                \
            a[ks], b[cb][ks], acc[rb][cb], 0, 0, 0);                          \
    __builtin_amdgcn_s_setprio(0);                                            \
  } while (0)

#define BAR do { __builtin_amdgcn_s_barrier(); asm volatile("" ::: "memory"); } while (0)

  // prologue: B(0), A(0), B(1) staged (12 gloads); wait all but B(1)
  stageHalf(Bm, bcol + 0,   &L[0][1][0][0], 0, srow, sc, wave);
  stageHalf(Bm, bcol + 128, &L[0][1][1][0], 0, srow, sc, wave);
  stageHalf(A,  brow + 0,   &L[0][0][0][0], 0, srow, sc, wave);
  stageHalf(A,  brow + 128, &L[0][0][1][0], 0, srow, sc, wave);
  stageHalf(Bm, bcol + 0,   &L[1][1][0][0], 1, srow, sc, wave);
  stageHalf(Bm, bcol + 128, &L[1][1][1][0], 1, srow, sc, wave);
  asm volatile("s_waitcnt vmcnt(4)" ::: "memory");
  BAR;

  for (int it = 0; it < NITER - 1; ++it) {
    const int s = 2 * it;
    // ph0: tile s row-block 0 (+ all B(s) frags); stage Ah0(s+1)
    RD_B(B0h); RD_A(A0h, 0);
    stageHalf(A, brow + 0,    &L[1][0][0][0], s + 1, srow, sc, wave);
    BAR; MM(0); BAR;
    // ph1
    RD_A(A0h, 1);
    stageHalf(A, brow + 128,  &L[1][0][1][0], s + 1, srow, sc, wave);
    BAR; MM(1); BAR;
    // ph2
    RD_A(A0h, 2);
    stageHalf(Bm, bcol + 0,   &L[0][1][0][0], s + 2, srow, sc, wave);
    BAR; MM(2); BAR;
    // ph3: checkpoint — A(s+1), B(s+1) landed; leave B(s+2) in flight
    RD_A(A0h, 3);
    stageHalf(Bm, bcol + 128, &L[0][1][1][0], s + 2, srow, sc, wave);
    BAR; MM(3);
    asm volatile("s_waitcnt vmcnt(4)" ::: "memory");
    BAR;
    // ph4: tile s+1 row-block 0
    RD_B(B1h); RD_A(A1h, 0);
    stageHalf(A, brow + 0,    &L[0][0][0][0], s + 2, srow, sc, wave);
    BAR; MM(0); BAR;
    // ph5
    RD_A(A1h, 1);
    stageHalf(A, brow + 128,  &L[0][0][1][0], s + 2, srow, sc, wave);
    BAR; MM(1); BAR;
    // ph6
    RD_A(A1h, 2);
    stageHalf(Bm, bcol + 0,   &L[1][1][0][0], s + 3, srow, sc, wave);
    BAR; MM(2); BAR;
    // ph7: checkpoint — A(s+2), B(s+2) landed; leave B(s+3) in flight
    RD_A(A1h, 3);
    stageHalf(Bm, bcol + 128, &L[1][1][1][0], s + 3, srow, sc, wave);
    BAR; MM(3);
    asm volatile("s_waitcnt vmcnt(4)" ::: "memory");
    BAR;
  }

  // peeled last iteration (tiles NT-2, NT-1): only A(NT-1) still to stage
  RD_B(B0h); RD_A(A0h, 0);
  stageHalf(A, brow + 0,   &L[1][0][0][0], NT - 1, srow, sc, wave);
  BAR; MM(0); BAR;
  RD_A(A0h, 1);
  stageHalf(A, brow + 128, &L[1][0][1][0], NT - 1, srow, sc, wave);
  BAR; MM(1); BAR;
  RD_A(A0h, 2); BAR; MM(2); BAR;
  RD_A(A0h, 3); BAR; MM(3);
  asm volatile("s_waitcnt vmcnt(0)" ::: "memory");
  BAR;
  RD_B(B1h); RD_A(A1h, 0); BAR; MM(0); BAR;
  RD_A(A1h, 1); BAR; MM(1); BAR;
  RD_A(A1h, 2); BAR; MM(2); BAR;
  RD_A(A1h, 3); BAR; MM(3);

#undef RD_A
#undef RD_B
#undef MM
#undef BAR

  // epilogue: 32x32 C/D layout col=lane&31, row=(reg&3)+8*(reg>>2)+4*(lane>>5)
  const int rowOff4 = ch2 << 2;
#pragma unroll
  for (int rb = 0; rb < 4; ++rb) {
    int rowbase = brow + (wm << 7) + rb * 32 + rowOff4;
#pragma unroll
    for (int cb = 0; cb < 2; ++cb) {
      int col = bcol + (wn << 6) + cb * 32 + laneRow;
      float bv = bias[col];
#pragma unroll
      for (int reg = 0; reg < 16; ++reg) {
        int row = rowbase + (reg & 3) + 8 * (reg >> 2);
        C[((size_t)row << 12) + col] = acc[rb][cb][reg] + bv;
      }
    }
  }
}

extern "C" void kernel_launch(void* const* d_in, const int* in_sizes, int n_in,
                              void* d_out, int out_size, void* d_ws, size_t ws_size,
                              hipStream_t stream) {
  const float* x     = (const float*)d_in[0];
  const float* psi   = (const float*)d_in[1];
  const float* omega = (const float*)d_in[2];
  const float* g     = (const float*)d_in[3];
  const float* bias  = (const float*)d_in[4];

  const int M = in_sizes[0] / DFEAT;   // 8192
  const int N = DFEAT;
  const int K = DFEAT;

  unsigned short* Wt = (unsigned short*)d_ws;                              // 32 MB
  unsigned short* Xb = (unsigned short*)((char*)d_ws + (size_t)N * K * 2); // 64 MB

  build_wt_kernel<<<DFEAT, 256, 0, stream>>>(psi, omega, g, Wt);

  int n8 = (M * K) / 8;
  convert_x_kernel<<<2048, 256, 0, stream>>>(x, Xb, n8);

  int nwg = (M / 256) * (N / 256);   // 32*16 = 512, divisible by 8
  gemm_kernel<<<nwg, 512, 0, stream>>>(Xb, Wt, bias, (float*)d_out, M);
}